// Round 1
// baseline (691.037 us; speedup 1.0000x reference)
//
#include <hip/hip_runtime.h>
#include <hip/hip_bf16.h>

// GCN: h1 = relu(GCNConv(x,W1,b1)); h2 = GCNConv(h1,W2,b2);
//      h3 = relu(h2@Wm1+bm1); out = h3@Wm2+bm2
// GCNConv(x,W,b): h = x@W; agg[dst] += h[src]*dinv[src]*dinv[dst];
//                 agg += h*dinv^2; out = agg + b   (deg from dst + self-loop)

namespace {

constexpr int N_NODES = 100000;
constexpr int N_EDGES = 1000000;

__global__ __launch_bounds__(256) void zero_kernel(int* cnt, int* flag, int n) {
  int i = blockIdx.x * 256 + threadIdx.x;
  if (i < n) cnt[i] = 0;
  if (i == 0) *flag = 0;
}

// edge_index may arrive as int32 or int64 depending on harness x64 config.
// Sample odd 32-bit words of the first 2E words: if the buffer is int64,
// those are high halves of nonneg values < 2^31 -> all zero. If int32,
// they are random node ids in [0,100000) -> essentially surely nonzero.
__global__ __launch_bounds__(256) void detect_kernel(const unsigned int* __restrict__ w, int* flag) {
  unsigned any = 0;
  int t = threadIdx.x;
  for (int s = 0; s < 8; s++) {
    long long pos = ((long long)(t * 8 + s) * 104729LL) % N_EDGES;
    any |= w[2 * pos + 1];
  }
  if (any) atomicOr(flag, 1);  // 1 => int32
}

__global__ __launch_bounds__(256) void convert_kernel(const void* __restrict__ ei,
                                                      const int* __restrict__ flag,
                                                      int* __restrict__ src, int* __restrict__ dst) {
  int i = blockIdx.x * 256 + threadIdx.x;
  if (i >= N_EDGES) return;
  if (*flag) {
    const int* p = (const int*)ei;
    src[i] = p[i];
    dst[i] = p[N_EDGES + i];
  } else {
    const long long* p = (const long long*)ei;
    src[i] = (int)p[i];
    dst[i] = (int)p[N_EDGES + i];
  }
}

__global__ __launch_bounds__(256) void degcount_kernel(const int* __restrict__ dst, int* __restrict__ cnt) {
  int i = blockIdx.x * 256 + threadIdx.x;
  if (i < N_EDGES) atomicAdd(&cnt[dst[i]], 1);
}

__global__ __launch_bounds__(256) void dinv_kernel(const int* __restrict__ cnt, float* __restrict__ dinv) {
  int i = blockIdx.x * 256 + threadIdx.x;
  if (i < N_NODES) dinv[i] = rsqrtf((float)cnt[i] + 1.0f);
}

__global__ __launch_bounds__(256) void norm_kernel(const int* __restrict__ src, const int* __restrict__ dst,
                                                   const float* __restrict__ dinv, float* __restrict__ nrm) {
  int i = blockIdx.x * 256 + threadIdx.x;
  if (i < N_EDGES) nrm[i] = dinv[src[i]] * dinv[dst[i]];
}

// C[n,F] = op(A[n,64]) @ W[64,F] (+bias) (relu). Block: 128 rows, 256 thr,
// thread = 4 rows x (F/8) cols. W staged in LDS; A read as float4 from global
// (row tile 32KB -> L1/L2-resident across the 8 col-groups re-reading it).
template <int F>
__global__ __launch_bounds__(256) void gemm_kernel(const float* __restrict__ A, const float* __restrict__ W,
                                                   const float* __restrict__ bias, float* __restrict__ C,
                                                   int n, int reluIn, int reluOut) {
  constexpr int CPT = F / 8;
  __shared__ float Ws[64 * F];
  int t = threadIdx.x;
  for (int i = t; i < 64 * F / 4; i += 256) ((float4*)Ws)[i] = ((const float4*)W)[i];
  __syncthreads();

  int rg = t >> 3, cg = t & 7;
  int r0 = blockIdx.x * 128 + rg * 4;
  int c0 = cg * CPT;

  float acc[4][CPT];
#pragma unroll
  for (int i = 0; i < 4; i++)
#pragma unroll
    for (int j = 0; j < CPT; j++) acc[i][j] = 0.f;

  const float4* A4 = (const float4*)A;
  for (int kk = 0; kk < 16; kk++) {
    float4 a[4];
#pragma unroll
    for (int i = 0; i < 4; i++) {
      int r = r0 + i;
      float4 v = (r < n) ? A4[(size_t)r * 16 + kk] : make_float4(0.f, 0.f, 0.f, 0.f);
      if (reluIn) {
        v.x = fmaxf(v.x, 0.f); v.y = fmaxf(v.y, 0.f);
        v.z = fmaxf(v.z, 0.f); v.w = fmaxf(v.w, 0.f);
      }
      a[i] = v;
    }
#pragma unroll
    for (int q = 0; q < 4; q++) {
      int k = kk * 4 + q;
      float w[CPT];
#pragma unroll
      for (int j = 0; j < CPT; j++) w[j] = Ws[k * F + c0 + j];
#pragma unroll
      for (int i = 0; i < 4; i++) {
        float av = q == 0 ? a[i].x : q == 1 ? a[i].y : q == 2 ? a[i].z : a[i].w;
#pragma unroll
        for (int j = 0; j < CPT; j++) acc[i][j] = fmaf(av, w[j], acc[i][j]);
      }
    }
  }

  float bv[CPT];
#pragma unroll
  for (int j = 0; j < CPT; j++) bv[j] = bias ? bias[c0 + j] : 0.f;
#pragma unroll
  for (int i = 0; i < 4; i++) {
    int r = r0 + i;
    if (r < n) {
      float* crow = C + (size_t)r * F + c0;
#pragma unroll
      for (int j = 0; j < CPT; j++) {
        float v = acc[i][j] + bv[j];
        if (reluOut) v = fmaxf(v, 0.f);
        crow[j] = v;
      }
    }
  }
}

// out[i][c] = h[i][c] * dinv[i]^2 + bias[c]   (self-loop term + bias, the
// base the edge scatter accumulates into). One float4 per thread.
__global__ __launch_bounds__(256) void selfloop_init_kernel(const float* __restrict__ h,
                                                            const float* __restrict__ dinv,
                                                            const float* __restrict__ bias,
                                                            float* __restrict__ out) {
  int i = blockIdx.x * 256 + threadIdx.x;
  if (i >= N_NODES * 16) return;
  int row = i >> 4, c4 = i & 15;
  float d = dinv[row];
  d = d * d;
  float4 hv = ((const float4*)h)[i];
  float4 bv = ((const float4*)bias)[c4];
  float4 o;
  o.x = fmaf(hv.x, d, bv.x);
  o.y = fmaf(hv.y, d, bv.y);
  o.z = fmaf(hv.z, d, bv.z);
  o.w = fmaf(hv.w, d, bv.w);
  ((float4*)out)[i] = o;
}

// One edge per 64-lane wave; lane = feature. Coalesced 256B gather of h[src],
// 64 native f32 atomics into agg[dst].
__global__ __launch_bounds__(256) void scatter_kernel(const float* __restrict__ h,
                                                      const int* __restrict__ src,
                                                      const int* __restrict__ dst,
                                                      const float* __restrict__ nrm,
                                                      float* __restrict__ agg) {
  int e = blockIdx.x * 4 + (threadIdx.x >> 6);
  int lane = threadIdx.x & 63;
  if (e >= N_EDGES) return;
  int s = src[e], d = dst[e];
  float nv = nrm[e];
  float v = h[(size_t)s * 64 + lane] * nv;
  unsafeAtomicAdd(&agg[(size_t)d * 64 + lane], v);
}

}  // namespace

extern "C" void kernel_launch(void* const* d_in, const int* in_sizes, int n_in,
                              void* d_out, int out_size, void* d_ws, size_t ws_size,
                              hipStream_t stream) {
  const float* x   = (const float*)d_in[0];
  const void*  ei  = d_in[1];
  const float* W1  = (const float*)d_in[2];
  const float* b1  = (const float*)d_in[3];
  const float* W2  = (const float*)d_in[4];
  const float* b2  = (const float*)d_in[5];
  const float* Wm1 = (const float*)d_in[6];
  const float* bm1 = (const float*)d_in[7];
  const float* Wm2 = (const float*)d_in[8];
  const float* bm2 = (const float*)d_in[9];
  float* out = (float*)d_out;

  char* ws = (char*)d_ws;
  size_t off = 0;
  auto alloc = [&](size_t bytes) -> void* {
    void* p = ws + off;
    off = (off + bytes + 511) & ~(size_t)511;
    return p;
  };
  int*   cnt  = (int*)  alloc((size_t)N_NODES * 4);
  float* dinv = (float*)alloc((size_t)N_NODES * 4);
  int*   flag = (int*)  alloc(4);
  int*   srcA = (int*)  alloc((size_t)N_EDGES * 4);
  int*   dstA = (int*)  alloc((size_t)N_EDGES * 4);
  float* nrm  = (float*)alloc((size_t)N_EDGES * 4);
  float* hA   = (float*)alloc((size_t)N_NODES * 64 * 4);
  float* hB   = (float*)alloc((size_t)N_NODES * 64 * 4);
  (void)ws_size; (void)in_sizes; (void)n_in; (void)out_size;

  dim3 b256(256);
  int gN   = (N_NODES + 255) / 256;
  int gE   = (N_EDGES + 255) / 256;
  int gGemm = (N_NODES + 127) / 128;
  int gInit = (N_NODES * 16 + 255) / 256;
  int gScat = (N_EDGES + 3) / 4;

  // graph preprocessing (shared by both convs)
  zero_kernel<<<gN, b256, 0, stream>>>(cnt, flag, N_NODES);
  detect_kernel<<<1, b256, 0, stream>>>((const unsigned int*)ei, flag);
  convert_kernel<<<gE, b256, 0, stream>>>(ei, flag, srcA, dstA);
  degcount_kernel<<<gE, b256, 0, stream>>>(dstA, cnt);
  dinv_kernel<<<gN, b256, 0, stream>>>(cnt, dinv);
  norm_kernel<<<gE, b256, 0, stream>>>(srcA, dstA, dinv, nrm);

  // conv1: hA = x@W1; hB = hA*dinv^2 + b1; hB[dst] += hA[src]*nrm
  gemm_kernel<64><<<gGemm, b256, 0, stream>>>(x, W1, nullptr, hA, N_NODES, 0, 0);
  selfloop_init_kernel<<<gInit, b256, 0, stream>>>(hA, dinv, b1, hB);
  scatter_kernel<<<gScat, b256, 0, stream>>>(hA, srcA, dstA, nrm, hB);

  // conv2: hA = relu(hB)@W2; hB = hA*dinv^2 + b2; hB[dst] += hA[src]*nrm
  gemm_kernel<64><<<gGemm, b256, 0, stream>>>(hB, W2, nullptr, hA, N_NODES, 1, 0);
  selfloop_init_kernel<<<gInit, b256, 0, stream>>>(hA, dinv, b2, hB);
  scatter_kernel<<<gScat, b256, 0, stream>>>(hA, srcA, dstA, nrm, hB);

  // MLP: hA = relu(hB@Wm1+bm1); out = hA@Wm2+bm2
  gemm_kernel<64><<<gGemm, b256, 0, stream>>>(hB, Wm1, bm1, hA, N_NODES, 0, 1);
  gemm_kernel<40><<<gGemm, b256, 0, stream>>>(hA, Wm2, bm2, out, N_NODES, 0, 0);
}

// Round 2
// 488.159 us; speedup vs baseline: 1.4156x; 1.4156x over previous
//
#include <hip/hip_runtime.h>
#include <hip/hip_bf16.h>

// GCN: h1 = relu(GCNConv(x,W1,b1)); h2 = GCNConv(h1,W2,b2);
//      h3 = relu(h2@Wm1+bm1); out = h3@Wm2+bm2
// GCNConv(x,W,b): h = x@W; agg[d] = sum_{e:dst=d} h[src_e]*dinv[src]*dinv[d]
//                 + h[d]*dinv[d]^2 + b
// R2: scatter-atomics (256MB atomic writes, 217us each) replaced by CSR-by-dst
// counting sort + per-node gather-reduce (one 256B store per node).

namespace {

constexpr int N_NODES = 100000;
constexpr int N_EDGES = 1000000;
constexpr int NB_SCAN = (N_NODES + 255) / 256;  // 391 scan blocks

__global__ __launch_bounds__(256) void zero_kernel(int* cnt, int* flag, int n) {
  int i = blockIdx.x * 256 + threadIdx.x;
  if (i < n) cnt[i] = 0;
  if (i == 0) *flag = 0;
}

// edge_index may arrive as int32 or int64. Sample odd 32-bit words: int64
// high halves of values < 2^31 are all zero; int32 node ids are ~surely not.
__global__ __launch_bounds__(256) void detect_kernel(const unsigned int* __restrict__ w, int* flag) {
  unsigned any = 0;
  int t = threadIdx.x;
  for (int s = 0; s < 8; s++) {
    long long pos = ((long long)(t * 8 + s) * 104729LL) % N_EDGES;
    any |= w[2 * pos + 1];
  }
  if (any) atomicOr(flag, 1);  // 1 => int32
}

__global__ __launch_bounds__(256) void convert_kernel(const void* __restrict__ ei,
                                                      const int* __restrict__ flag,
                                                      int* __restrict__ src, int* __restrict__ dst) {
  int i = blockIdx.x * 256 + threadIdx.x;
  if (i >= N_EDGES) return;
  if (*flag) {
    const int* p = (const int*)ei;
    src[i] = p[i];
    dst[i] = p[N_EDGES + i];
  } else {
    const long long* p = (const long long*)ei;
    src[i] = (int)p[i];
    dst[i] = (int)p[N_EDGES + i];
  }
}

__global__ __launch_bounds__(256) void degcount_kernel(const int* __restrict__ dst, int* __restrict__ cnt) {
  int i = blockIdx.x * 256 + threadIdx.x;
  if (i < N_EDGES) atomicAdd(&cnt[dst[i]], 1);
}

__global__ __launch_bounds__(256) void dinv_kernel(const int* __restrict__ cnt, float* __restrict__ dinv) {
  int i = blockIdx.x * 256 + threadIdx.x;
  if (i < N_NODES) dinv[i] = rsqrtf((float)cnt[i] + 1.0f);
}

// --- 3-kernel exclusive scan of cnt[N_NODES] -> row_ptr ---
__global__ __launch_bounds__(256) void scan1_kernel(const int* __restrict__ cnt,
                                                    int* __restrict__ local, int* __restrict__ bsum) {
  __shared__ int s[256];
  int i = blockIdx.x * 256 + threadIdx.x;
  int v = (i < N_NODES) ? cnt[i] : 0;
  s[threadIdx.x] = v;
  __syncthreads();
#pragma unroll
  for (int off = 1; off < 256; off <<= 1) {
    int t = (threadIdx.x >= off) ? s[threadIdx.x - off] : 0;
    __syncthreads();
    s[threadIdx.x] += t;
    __syncthreads();
  }
  if (i < N_NODES) local[i] = s[threadIdx.x] - v;  // exclusive
  if (threadIdx.x == 255) bsum[blockIdx.x] = s[255];
}

__global__ __launch_bounds__(512) void scan2_kernel(int* __restrict__ bsum, int* __restrict__ boff) {
  __shared__ int s[512];
  int t = threadIdx.x;
  int v = (t < NB_SCAN) ? bsum[t] : 0;
  s[t] = v;
  __syncthreads();
#pragma unroll
  for (int off = 1; off < 512; off <<= 1) {
    int u = (t >= off) ? s[t - off] : 0;
    __syncthreads();
    s[t] += u;
    __syncthreads();
  }
  if (t < NB_SCAN) boff[t] = s[t] - v;  // exclusive
}

__global__ __launch_bounds__(256) void scan3_kernel(const int* __restrict__ local,
                                                    const int* __restrict__ boff,
                                                    const int* __restrict__ cnt,
                                                    int* __restrict__ row_ptr, int* __restrict__ cursor) {
  int i = blockIdx.x * 256 + threadIdx.x;
  if (i < N_NODES) {
    int r = local[i] + boff[blockIdx.x];
    row_ptr[i] = r;
    cursor[i] = r;
    if (i == N_NODES - 1) row_ptr[N_NODES] = r + cnt[i];
  }
}

__global__ __launch_bounds__(256) void fill_kernel(const int* __restrict__ src, const int* __restrict__ dst,
                                                   const float* __restrict__ dinv,
                                                   int* __restrict__ cursor,
                                                   int* __restrict__ col, float* __restrict__ val) {
  int e = blockIdx.x * 256 + threadIdx.x;
  if (e >= N_EDGES) return;
  int d = dst[e], s = src[e];
  int pos = atomicAdd(&cursor[d], 1);
  col[pos] = s;
  val[pos] = dinv[s] * dinv[d];
}

// C[n,F] = op(A[n,64]) @ W[64,F] (+bias) (relu). Block: 128 rows, 256 thr,
// thread = 4 rows x (F/8) cols. W staged in LDS; A read as float4.
template <int F>
__global__ __launch_bounds__(256) void gemm_kernel(const float* __restrict__ A, const float* __restrict__ W,
                                                   const float* __restrict__ bias, float* __restrict__ C,
                                                   int n, int reluIn, int reluOut) {
  constexpr int CPT = F / 8;
  __shared__ float Ws[64 * F];
  int t = threadIdx.x;
  for (int i = t; i < 64 * F / 4; i += 256) ((float4*)Ws)[i] = ((const float4*)W)[i];
  __syncthreads();

  int rg = t >> 3, cg = t & 7;
  int r0 = blockIdx.x * 128 + rg * 4;
  int c0 = cg * CPT;

  float acc[4][CPT];
#pragma unroll
  for (int i = 0; i < 4; i++)
#pragma unroll
    for (int j = 0; j < CPT; j++) acc[i][j] = 0.f;

  const float4* A4 = (const float4*)A;
  for (int kk = 0; kk < 16; kk++) {
    float4 a[4];
#pragma unroll
    for (int i = 0; i < 4; i++) {
      int r = r0 + i;
      float4 v = (r < n) ? A4[(size_t)r * 16 + kk] : make_float4(0.f, 0.f, 0.f, 0.f);
      if (reluIn) {
        v.x = fmaxf(v.x, 0.f); v.y = fmaxf(v.y, 0.f);
        v.z = fmaxf(v.z, 0.f); v.w = fmaxf(v.w, 0.f);
      }
      a[i] = v;
    }
#pragma unroll
    for (int q = 0; q < 4; q++) {
      int k = kk * 4 + q;
      float w[CPT];
#pragma unroll
      for (int j = 0; j < CPT; j++) w[j] = Ws[k * F + c0 + j];
#pragma unroll
      for (int i = 0; i < 4; i++) {
        float av = q == 0 ? a[i].x : q == 1 ? a[i].y : q == 2 ? a[i].z : a[i].w;
#pragma unroll
        for (int j = 0; j < CPT; j++) acc[i][j] = fmaf(av, w[j], acc[i][j]);
      }
    }
  }

  float bv[CPT];
#pragma unroll
  for (int j = 0; j < CPT; j++) bv[j] = bias ? bias[c0 + j] : 0.f;
#pragma unroll
  for (int i = 0; i < 4; i++) {
    int r = r0 + i;
    if (r < n) {
      float* crow = C + (size_t)r * F + c0;
#pragma unroll
      for (int j = 0; j < CPT; j++) {
        float v = acc[i][j] + bv[j];
        if (reluOut) v = fmaxf(v, 0.f);
        crow[j] = v;
      }
    }
  }
}

// Per-node gather-reduce: one 64-lane wave per node, lane = feature.
// out[d] = h[d]*dinv[d]^2 + bias + sum_e h[col[e]]*val[e]; single store.
__global__ __launch_bounds__(256) void aggregate_kernel(const float* __restrict__ h,
                                                        const int* __restrict__ row_ptr,
                                                        const int* __restrict__ col,
                                                        const float* __restrict__ val,
                                                        const float* __restrict__ dinv,
                                                        const float* __restrict__ bias,
                                                        float* __restrict__ out) {
  int d = blockIdx.x * 4 + (threadIdx.x >> 6);
  int lane = threadIdx.x & 63;
  if (d >= N_NODES) return;
  int e0 = row_ptr[d], e1 = row_ptr[d + 1];
  float dv = dinv[d];
  float acc = fmaf(h[(size_t)d * 64 + lane], dv * dv, bias[lane]);
  int e = e0;
  // 2-deep software pipeline on the col/val -> h dependent chain
  if (e < e1) {
    int c = col[e];
    float v = val[e];
    for (; e + 1 < e1; e++) {
      int c2 = col[e + 1];
      float v2 = val[e + 1];
      float hv = h[(size_t)c * 64 + lane];
      c = c2;
      acc = fmaf(hv, v, acc);
      v = v2;
    }
    acc = fmaf(h[(size_t)c * 64 + lane], v, acc);
  }
  out[(size_t)d * 64 + lane] = acc;
}

}  // namespace

extern "C" void kernel_launch(void* const* d_in, const int* in_sizes, int n_in,
                              void* d_out, int out_size, void* d_ws, size_t ws_size,
                              hipStream_t stream) {
  const float* x   = (const float*)d_in[0];
  const void*  ei  = d_in[1];
  const float* W1  = (const float*)d_in[2];
  const float* b1  = (const float*)d_in[3];
  const float* W2  = (const float*)d_in[4];
  const float* b2  = (const float*)d_in[5];
  const float* Wm1 = (const float*)d_in[6];
  const float* bm1 = (const float*)d_in[7];
  const float* Wm2 = (const float*)d_in[8];
  const float* bm2 = (const float*)d_in[9];
  float* out = (float*)d_out;

  char* ws = (char*)d_ws;
  size_t off = 0;
  auto alloc = [&](size_t bytes) -> void* {
    void* p = ws + off;
    off = (off + bytes + 511) & ~(size_t)511;
    return p;
  };
  int*   cnt    = (int*)  alloc((size_t)N_NODES * 4);
  float* dinv   = (float*)alloc((size_t)N_NODES * 4);
  int*   flag   = (int*)  alloc(4);
  int*   srcA   = (int*)  alloc((size_t)N_EDGES * 4);
  int*   dstA   = (int*)  alloc((size_t)N_EDGES * 4);
  int*   colA   = (int*)  alloc((size_t)N_EDGES * 4);
  float* valA   = (float*)alloc((size_t)N_EDGES * 4);
  int*   rowp   = (int*)  alloc((size_t)(N_NODES + 1) * 4);
  int*   cursor = (int*)  alloc((size_t)N_NODES * 4);
  int*   slocal = (int*)  alloc((size_t)N_NODES * 4);
  int*   bsum   = (int*)  alloc((size_t)NB_SCAN * 4);
  int*   boff   = (int*)  alloc((size_t)NB_SCAN * 4);
  float* hA     = (float*)alloc((size_t)N_NODES * 64 * 4);
  float* hB     = (float*)alloc((size_t)N_NODES * 64 * 4);
  (void)ws_size; (void)in_sizes; (void)n_in; (void)out_size;

  dim3 b256(256);
  int gN    = (N_NODES + 255) / 256;
  int gE    = (N_EDGES + 255) / 256;
  int gGemm = (N_NODES + 127) / 128;
  int gAgg  = (N_NODES + 3) / 4;

  // graph preprocessing (shared by both convs): CSR by dst via counting sort
  zero_kernel<<<gN, b256, 0, stream>>>(cnt, flag, N_NODES);
  detect_kernel<<<1, b256, 0, stream>>>((const unsigned int*)ei, flag);
  convert_kernel<<<gE, b256, 0, stream>>>(ei, flag, srcA, dstA);
  degcount_kernel<<<gE, b256, 0, stream>>>(dstA, cnt);
  dinv_kernel<<<gN, b256, 0, stream>>>(cnt, dinv);
  scan1_kernel<<<NB_SCAN, b256, 0, stream>>>(cnt, slocal, bsum);
  scan2_kernel<<<1, dim3(512), 0, stream>>>(bsum, boff);
  scan3_kernel<<<NB_SCAN, b256, 0, stream>>>(slocal, boff, cnt, rowp, cursor);
  fill_kernel<<<gE, b256, 0, stream>>>(srcA, dstA, dinv, cursor, colA, valA);

  // conv1: hA = x@W1; hB = aggregate(hA) + b1
  gemm_kernel<64><<<gGemm, b256, 0, stream>>>(x, W1, nullptr, hA, N_NODES, 0, 0);
  aggregate_kernel<<<gAgg, b256, 0, stream>>>(hA, rowp, colA, valA, dinv, b1, hB);

  // conv2: hA = relu(hB)@W2; hB = aggregate(hA) + b2
  gemm_kernel<64><<<gGemm, b256, 0, stream>>>(hB, W2, nullptr, hA, N_NODES, 1, 0);
  aggregate_kernel<<<gAgg, b256, 0, stream>>>(hA, rowp, colA, valA, dinv, b2, hB);

  // MLP: hA = relu(hB@Wm1+bm1); out = hA@Wm2+bm2
  gemm_kernel<64><<<gGemm, b256, 0, stream>>>(hB, Wm1, bm1, hA, N_NODES, 0, 1);
  gemm_kernel<40><<<gGemm, b256, 0, stream>>>(hA, Wm2, bm2, out, N_NODES, 0, 0);
}

// Round 3
// 395.497 us; speedup vs baseline: 1.7473x; 1.2343x over previous
//
#include <hip/hip_runtime.h>
#include <hip/hip_bf16.h>

// GCN: h1 = relu(GCNConv(x,W1,b1)); h2 = GCNConv(h1,W2,b2);
//      h3 = relu(h2@Wm1+bm1); out = h3@Wm2+bm2
// GCNConv(x,W,b): h = x@W; agg[d] = sum_{e:dst=d} h[src_e]*dinv[src]*dinv[d]
//                 + h[d]*dinv[d]^2 + b
// R2: CSR-by-dst gather-reduce (one wave per node) replaced scatter atomics.
// R3: aggregate edge loop unrolled 4-wide (4 gathers in flight, 4 accs) --
//     R2 counters showed latency-bound (hbm 20%, VALU 16%); (col,val) packed
//     into one int2 broadcast load; GEMM W-reads as explicit float4.

namespace {

constexpr int N_NODES = 100000;
constexpr int N_EDGES = 1000000;
constexpr int NB_SCAN = (N_NODES + 255) / 256;  // 391 scan blocks

__global__ __launch_bounds__(256) void zero_kernel(int* cnt, int* flag, int n) {
  int i = blockIdx.x * 256 + threadIdx.x;
  if (i < n) cnt[i] = 0;
  if (i == 0) *flag = 0;
}

// edge_index may arrive as int32 or int64. Sample odd 32-bit words: int64
// high halves of values < 2^31 are all zero; int32 node ids are ~surely not.
__global__ __launch_bounds__(256) void detect_kernel(const unsigned int* __restrict__ w, int* flag) {
  unsigned any = 0;
  int t = threadIdx.x;
  for (int s = 0; s < 8; s++) {
    long long pos = ((long long)(t * 8 + s) * 104729LL) % N_EDGES;
    any |= w[2 * pos + 1];
  }
  if (any) atomicOr(flag, 1);  // 1 => int32
}

__global__ __launch_bounds__(256) void convert_kernel(const void* __restrict__ ei,
                                                      const int* __restrict__ flag,
                                                      int* __restrict__ src, int* __restrict__ dst) {
  int i = blockIdx.x * 256 + threadIdx.x;
  if (i >= N_EDGES) return;
  if (*flag) {
    const int* p = (const int*)ei;
    src[i] = p[i];
    dst[i] = p[N_EDGES + i];
  } else {
    const long long* p = (const long long*)ei;
    src[i] = (int)p[i];
    dst[i] = (int)p[N_EDGES + i];
  }
}

__global__ __launch_bounds__(256) void degcount_kernel(const int* __restrict__ dst, int* __restrict__ cnt) {
  int i = blockIdx.x * 256 + threadIdx.x;
  if (i < N_EDGES) atomicAdd(&cnt[dst[i]], 1);
}

__global__ __launch_bounds__(256) void dinv_kernel(const int* __restrict__ cnt, float* __restrict__ dinv) {
  int i = blockIdx.x * 256 + threadIdx.x;
  if (i < N_NODES) dinv[i] = rsqrtf((float)cnt[i] + 1.0f);
}

// --- 3-kernel exclusive scan of cnt[N_NODES] -> row_ptr ---
__global__ __launch_bounds__(256) void scan1_kernel(const int* __restrict__ cnt,
                                                    int* __restrict__ local, int* __restrict__ bsum) {
  __shared__ int s[256];
  int i = blockIdx.x * 256 + threadIdx.x;
  int v = (i < N_NODES) ? cnt[i] : 0;
  s[threadIdx.x] = v;
  __syncthreads();
#pragma unroll
  for (int off = 1; off < 256; off <<= 1) {
    int t = (threadIdx.x >= off) ? s[threadIdx.x - off] : 0;
    __syncthreads();
    s[threadIdx.x] += t;
    __syncthreads();
  }
  if (i < N_NODES) local[i] = s[threadIdx.x] - v;  // exclusive
  if (threadIdx.x == 255) bsum[blockIdx.x] = s[255];
}

__global__ __launch_bounds__(512) void scan2_kernel(int* __restrict__ bsum, int* __restrict__ boff) {
  __shared__ int s[512];
  int t = threadIdx.x;
  int v = (t < NB_SCAN) ? bsum[t] : 0;
  s[t] = v;
  __syncthreads();
#pragma unroll
  for (int off = 1; off < 512; off <<= 1) {
    int u = (t >= off) ? s[t - off] : 0;
    __syncthreads();
    s[t] += u;
    __syncthreads();
  }
  if (t < NB_SCAN) boff[t] = s[t] - v;  // exclusive
}

__global__ __launch_bounds__(256) void scan3_kernel(const int* __restrict__ local,
                                                    const int* __restrict__ boff,
                                                    const int* __restrict__ cnt,
                                                    int* __restrict__ row_ptr, int* __restrict__ cursor) {
  int i = blockIdx.x * 256 + threadIdx.x;
  if (i < N_NODES) {
    int r = local[i] + boff[blockIdx.x];
    row_ptr[i] = r;
    cursor[i] = r;
    if (i == N_NODES - 1) row_ptr[N_NODES] = r + cnt[i];
  }
}

// packs (src, dinv[src]*dinv[dst]) into one int2 per CSR slot
__global__ __launch_bounds__(256) void fill_kernel(const int* __restrict__ src, const int* __restrict__ dst,
                                                   const float* __restrict__ dinv,
                                                   int* __restrict__ cursor,
                                                   int2* __restrict__ ev) {
  int e = blockIdx.x * 256 + threadIdx.x;
  if (e >= N_EDGES) return;
  int d = dst[e], s = src[e];
  int pos = atomicAdd(&cursor[d], 1);
  ev[pos] = make_int2(s, __float_as_int(dinv[s] * dinv[d]));
}

// C[n,F] = op(A[n,64]) @ W[64,F] (+bias) (relu). Block: 128 rows, 256 thr,
// thread = 4 rows x (F/8) cols. W staged in LDS; A read as float4.
template <int F>
__global__ __launch_bounds__(256) void gemm_kernel(const float* __restrict__ A, const float* __restrict__ W,
                                                   const float* __restrict__ bias, float* __restrict__ C,
                                                   int n, int reluIn, int reluOut) {
  constexpr int CPT = F / 8;
  __shared__ float Ws[64 * F];
  int t = threadIdx.x;
  for (int i = t; i < 64 * F / 4; i += 256) ((float4*)Ws)[i] = ((const float4*)W)[i];
  __syncthreads();

  int rg = t >> 3, cg = t & 7;
  int r0 = blockIdx.x * 128 + rg * 4;
  int c0 = cg * CPT;

  float acc[4][CPT];
#pragma unroll
  for (int i = 0; i < 4; i++)
#pragma unroll
    for (int j = 0; j < CPT; j++) acc[i][j] = 0.f;

  const float4* A4 = (const float4*)A;
  for (int kk = 0; kk < 16; kk++) {
    float4 a[4];
#pragma unroll
    for (int i = 0; i < 4; i++) {
      int r = r0 + i;
      float4 v = (r < n) ? A4[(size_t)r * 16 + kk] : make_float4(0.f, 0.f, 0.f, 0.f);
      if (reluIn) {
        v.x = fmaxf(v.x, 0.f); v.y = fmaxf(v.y, 0.f);
        v.z = fmaxf(v.z, 0.f); v.w = fmaxf(v.w, 0.f);
      }
      a[i] = v;
    }
#pragma unroll
    for (int q = 0; q < 4; q++) {
      int k = kk * 4 + q;
      float w[CPT];
      if constexpr (CPT % 4 == 0) {
#pragma unroll
        for (int j = 0; j < CPT / 4; j++)
          *(float4*)&w[4 * j] = *(const float4*)&Ws[k * F + c0 + 4 * j];  // ds_read_b128
      } else {
#pragma unroll
        for (int j = 0; j < CPT; j++) w[j] = Ws[k * F + c0 + j];
      }
#pragma unroll
      for (int i = 0; i < 4; i++) {
        float av = q == 0 ? a[i].x : q == 1 ? a[i].y : q == 2 ? a[i].z : a[i].w;
#pragma unroll
        for (int j = 0; j < CPT; j++) acc[i][j] = fmaf(av, w[j], acc[i][j]);
      }
    }
  }

  float bv[CPT];
#pragma unroll
  for (int j = 0; j < CPT; j++) bv[j] = bias ? bias[c0 + j] : 0.f;
#pragma unroll
  for (int i = 0; i < 4; i++) {
    int r = r0 + i;
    if (r < n) {
      float* crow = C + (size_t)r * F + c0;
#pragma unroll
      for (int j = 0; j < CPT; j++) {
        float v = acc[i][j] + bv[j];
        if (reluOut) v = fmaxf(v, 0.f);
        crow[j] = v;
      }
    }
  }
}

// Per-node gather-reduce: one 64-lane wave per node, lane = feature.
// out[d] = h[d]*dinv[d]^2 + bias + sum_e h[ev.x]*ev.y; single store.
// Edge loop unrolled 4-wide: 4 independent h gathers in flight, 4 accs.
__global__ __launch_bounds__(256) void aggregate_kernel(const float* __restrict__ h,
                                                        const int* __restrict__ row_ptr,
                                                        const int2* __restrict__ ev,
                                                        const float* __restrict__ dinv,
                                                        const float* __restrict__ bias,
                                                        float* __restrict__ out) {
  int d = blockIdx.x * 4 + (threadIdx.x >> 6);
  int lane = threadIdx.x & 63;
  if (d >= N_NODES) return;
  int e0 = row_ptr[d], e1 = row_ptr[d + 1];
  float dv = dinv[d];
  float self = h[(size_t)d * 64 + lane];
  float bl = bias[lane];
  float acc0 = fmaf(self, dv * dv, bl);
  float acc1 = 0.f, acc2 = 0.f, acc3 = 0.f;
  int e = e0;
  for (; e + 4 <= e1; e += 4) {
    int2 p0 = ev[e];
    int2 p1 = ev[e + 1];
    int2 p2 = ev[e + 2];
    int2 p3 = ev[e + 3];
    float h0 = h[(size_t)p0.x * 64 + lane];
    float h1 = h[(size_t)p1.x * 64 + lane];
    float h2 = h[(size_t)p2.x * 64 + lane];
    float h3 = h[(size_t)p3.x * 64 + lane];
    acc0 = fmaf(h0, __int_as_float(p0.y), acc0);
    acc1 = fmaf(h1, __int_as_float(p1.y), acc1);
    acc2 = fmaf(h2, __int_as_float(p2.y), acc2);
    acc3 = fmaf(h3, __int_as_float(p3.y), acc3);
  }
  for (; e < e1; e++) {
    int2 p = ev[e];
    acc0 = fmaf(h[(size_t)p.x * 64 + lane], __int_as_float(p.y), acc0);
  }
  out[(size_t)d * 64 + lane] = (acc0 + acc1) + (acc2 + acc3);
}

}  // namespace

extern "C" void kernel_launch(void* const* d_in, const int* in_sizes, int n_in,
                              void* d_out, int out_size, void* d_ws, size_t ws_size,
                              hipStream_t stream) {
  const float* x   = (const float*)d_in[0];
  const void*  ei  = d_in[1];
  const float* W1  = (const float*)d_in[2];
  const float* b1  = (const float*)d_in[3];
  const float* W2  = (const float*)d_in[4];
  const float* b2  = (const float*)d_in[5];
  const float* Wm1 = (const float*)d_in[6];
  const float* bm1 = (const float*)d_in[7];
  const float* Wm2 = (const float*)d_in[8];
  const float* bm2 = (const float*)d_in[9];
  float* out = (float*)d_out;

  char* ws = (char*)d_ws;
  size_t off = 0;
  auto alloc = [&](size_t bytes) -> void* {
    void* p = ws + off;
    off = (off + bytes + 511) & ~(size_t)511;
    return p;
  };
  int*   cnt    = (int*)  alloc((size_t)N_NODES * 4);
  float* dinv   = (float*)alloc((size_t)N_NODES * 4);
  int*   flag   = (int*)  alloc(4);
  int*   srcA   = (int*)  alloc((size_t)N_EDGES * 4);
  int*   dstA   = (int*)  alloc((size_t)N_EDGES * 4);
  int2*  ev     = (int2*) alloc((size_t)N_EDGES * 8);
  int*   rowp   = (int*)  alloc((size_t)(N_NODES + 1) * 4);
  int*   cursor = (int*)  alloc((size_t)N_NODES * 4);
  int*   slocal = (int*)  alloc((size_t)N_NODES * 4);
  int*   bsum   = (int*)  alloc((size_t)NB_SCAN * 4);
  int*   boff   = (int*)  alloc((size_t)NB_SCAN * 4);
  float* hA     = (float*)alloc((size_t)N_NODES * 64 * 4);
  float* hB     = (float*)alloc((size_t)N_NODES * 64 * 4);
  (void)ws_size; (void)in_sizes; (void)n_in; (void)out_size;

  dim3 b256(256);
  int gN    = (N_NODES + 255) / 256;
  int gE    = (N_EDGES + 255) / 256;
  int gGemm = (N_NODES + 127) / 128;
  int gAgg  = (N_NODES + 3) / 4;

  // graph preprocessing (shared by both convs): CSR by dst via counting sort
  zero_kernel<<<gN, b256, 0, stream>>>(cnt, flag, N_NODES);
  detect_kernel<<<1, b256, 0, stream>>>((const unsigned int*)ei, flag);
  convert_kernel<<<gE, b256, 0, stream>>>(ei, flag, srcA, dstA);
  degcount_kernel<<<gE, b256, 0, stream>>>(dstA, cnt);
  dinv_kernel<<<gN, b256, 0, stream>>>(cnt, dinv);
  scan1_kernel<<<NB_SCAN, b256, 0, stream>>>(cnt, slocal, bsum);
  scan2_kernel<<<1, dim3(512), 0, stream>>>(bsum, boff);
  scan3_kernel<<<NB_SCAN, b256, 0, stream>>>(slocal, boff, cnt, rowp, cursor);
  fill_kernel<<<gE, b256, 0, stream>>>(srcA, dstA, dinv, cursor, ev);

  // conv1: hA = x@W1; hB = aggregate(hA) + b1
  gemm_kernel<64><<<gGemm, b256, 0, stream>>>(x, W1, nullptr, hA, N_NODES, 0, 0);
  aggregate_kernel<<<gAgg, b256, 0, stream>>>(hA, rowp, ev, dinv, b1, hB);

  // conv2: hA = relu(hB)@W2; hB = aggregate(hA) + b2
  gemm_kernel<64><<<gGemm, b256, 0, stream>>>(hB, W2, nullptr, hA, N_NODES, 1, 0);
  aggregate_kernel<<<gAgg, b256, 0, stream>>>(hA, rowp, ev, dinv, b2, hB);

  // MLP: hA = relu(hB@Wm1+bm1); out = hA@Wm2+bm2
  gemm_kernel<64><<<gGemm, b256, 0, stream>>>(hB, Wm1, bm1, hA, N_NODES, 0, 1);
  gemm_kernel<40><<<gGemm, b256, 0, stream>>>(hA, Wm2, bm2, out, N_NODES, 0, 0);
}

// Round 4
// 382.464 us; speedup vs baseline: 1.8068x; 1.0341x over previous
//
#include <hip/hip_runtime.h>
#include <hip/hip_bf16.h>

// GCN: h1 = relu(GCNConv(x,W1,b1)); h2 = GCNConv(h1,W2,b2);
//      h3 = relu(h2@Wm1+bm1); out = h3@Wm2+bm2
// GCNConv(x,W,b): h = x@W; agg[d] = sum_{e:dst=d} h[src_e]*dinv[src]*dinv[d]
//                 + h[d]*dinv[d]^2 + b
// R2: CSR-by-dst gather-reduce (one wave per node) replaced scatter atomics.
// R3: aggregate edge loop unrolled (latency-bound gather chain).
// R4: fill_kernel showed 8x HBM write amplification (66MB for an 8MB array:
//     CSR lines written by threads on all 8 XCDs). Replaced by 2-pass bucket
//     sort: passA partitions into 196 x 512-node buckets (block-local runs),
//     passB sorts each bucket entirely in LDS and writes its private CSR
//     segment from ONE workgroup (one XCD -> amplification ~1). passB also
//     emits row_ptr + dinv (deletes degcount/scan x3/dinv/convert/fill).
//     val computed on the fly in aggregate from dinv; aggregate unroll 8,
//     predicated (no serial remainder tail).

namespace {

constexpr int N_NODES = 100000;
constexpr int N_EDGES = 1000000;
constexpr int NBUCK = (N_NODES + 511) / 512;  // 196 buckets of 512 nodes
constexpr int CAP = 8192;                     // bucket capacity (mean 5120, sigma ~71)
constexpr int EPB_A = 2048;                   // edges per passA block

// Zero bucket counters + int32/int64 detection for edge_index.
// int64 high halves of values < 2^31 are all zero; int32 node ids are not.
__global__ __launch_bounds__(256) void zero_detect_kernel(int* bucketCnt, int* flag,
                                                          const unsigned int* __restrict__ w) {
  int t = threadIdx.x;
  if (t < NBUCK) bucketCnt[t] = 0;
  if (t == 0) *flag = 0;
  __syncthreads();
  unsigned any = 0;
  for (int s = 0; s < 8; s++) {
    long long pos = ((long long)(t * 8 + s) * 104729LL) % N_EDGES;
    any |= w[2 * pos + 1];
  }
  if (any) atomicOr(flag, 1);  // 1 => int32
}

// passA: partition edges into NBUCK buckets by dst>>9. Packed word =
// (src<<9)|(dst&511) (src<2^17, fits). Block-local LDS histogram, one global
// atomicAdd per touched bucket, then per-block contiguous runs into tmp.
__global__ __launch_bounds__(256) void bucket_kernel(const void* __restrict__ ei,
                                                     const int* __restrict__ flag,
                                                     int* __restrict__ bucketCnt,
                                                     unsigned* __restrict__ tmp) {
  __shared__ int hist[NBUCK];
  __shared__ int basePB[NBUCK];
  __shared__ int cur[NBUCK];
  int t = threadIdx.x;
  if (t < NBUCK) { hist[t] = 0; cur[t] = 0; }
  __syncthreads();

  int e0 = blockIdx.x * EPB_A;
  int is32 = *flag;
  unsigned wreg[8];
  int breg[8];
#pragma unroll
  for (int k = 0; k < 8; k++) {
    int e = e0 + k * 256 + t;
    breg[k] = -1;
    if (e < N_EDGES) {
      int s, d;
      if (is32) {
        const int* p = (const int*)ei;
        s = p[e]; d = p[N_EDGES + e];
      } else {
        const long long* p = (const long long*)ei;
        s = (int)p[e]; d = (int)p[N_EDGES + e];
      }
      wreg[k] = ((unsigned)s << 9) | (unsigned)(d & 511);
      breg[k] = d >> 9;
      atomicAdd(&hist[breg[k]], 1);
    }
  }
  __syncthreads();
  if (t < NBUCK) basePB[t] = hist[t] ? atomicAdd(&bucketCnt[t], hist[t]) : 0;
  __syncthreads();
#pragma unroll
  for (int k = 0; k < 8; k++) {
    if (breg[k] >= 0) {
      int r = atomicAdd(&cur[breg[k]], 1);
      tmp[(size_t)breg[k] * CAP + basePB[breg[k]] + r] = wreg[k];
    }
  }
}

// passB: one block per bucket. Stage bucket in LDS, 512-bin counting sort,
// write col (src) into this bucket's private CSR segment; emit row_ptr+dinv.
__global__ __launch_bounds__(512) void csr_kernel(const unsigned* __restrict__ tmp,
                                                  const int* __restrict__ bucketCnt,
                                                  int* __restrict__ col,
                                                  int* __restrict__ row_ptr,
                                                  float* __restrict__ dinv) {
  __shared__ int sc[512];
  __shared__ int hist[512];
  __shared__ unsigned stage[CAP];
  int b = blockIdx.x, t = threadIdx.x;

  // exclusive prefix of bucketCnt -> global base of this bucket's segment
  sc[t] = (t < NBUCK) ? bucketCnt[t] : 0;
  __syncthreads();
#pragma unroll
  for (int off = 1; off < 512; off <<= 1) {
    int u = (t >= off) ? sc[t - off] : 0;
    __syncthreads();
    sc[t] += u;
    __syncthreads();
  }
  int base = (b > 0) ? sc[b - 1] : 0;
  int myCnt = bucketCnt[b];
  __syncthreads();

  hist[t] = 0;
  __syncthreads();
  for (int i = t; i < myCnt; i += 512) {
    unsigned w = tmp[(size_t)b * CAP + i];
    stage[i] = w;
    atomicAdd(&hist[w & 511u], 1);
  }
  __syncthreads();

  // scan hist (inclusive) -> per-node offsets within bucket
  sc[t] = hist[t];
  __syncthreads();
#pragma unroll
  for (int off = 1; off < 512; off <<= 1) {
    int u = (t >= off) ? sc[t - off] : 0;
    __syncthreads();
    sc[t] += u;
    __syncthreads();
  }
  int excl = sc[t] - hist[t];
  int d = b * 512 + t;
  if (d < N_NODES) {
    row_ptr[d] = base + excl;
    dinv[d] = rsqrtf((float)hist[t] + 1.0f);
  }
  if (b == NBUCK - 1 && t == 0) row_ptr[N_NODES] = N_EDGES;
  int deg = hist[t];  // keep own count before reuse
  (void)deg;
  __syncthreads();
  hist[t] = excl;  // reuse hist as write cursor
  __syncthreads();
  for (int i = t; i < myCnt; i += 512) {
    unsigned w = stage[i];
    int pos = atomicAdd(&hist[w & 511u], 1);
    col[base + pos] = (int)(w >> 9);
  }
}

// C[n,F] = op(A[n,64]) @ W[64,F] (+bias) (relu). Block: 128 rows, 256 thr,
// thread = 4 rows x (F/8) cols. W staged in LDS; A read as float4.
template <int F>
__global__ __launch_bounds__(256) void gemm_kernel(const float* __restrict__ A, const float* __restrict__ W,
                                                   const float* __restrict__ bias, float* __restrict__ C,
                                                   int n, int reluIn, int reluOut) {
  constexpr int CPT = F / 8;
  __shared__ float Ws[64 * F];
  int t = threadIdx.x;
  for (int i = t; i < 64 * F / 4; i += 256) ((float4*)Ws)[i] = ((const float4*)W)[i];
  __syncthreads();

  int rg = t >> 3, cg = t & 7;
  int r0 = blockIdx.x * 128 + rg * 4;
  int c0 = cg * CPT;

  float acc[4][CPT];
#pragma unroll
  for (int i = 0; i < 4; i++)
#pragma unroll
    for (int j = 0; j < CPT; j++) acc[i][j] = 0.f;

  const float4* A4 = (const float4*)A;
  for (int kk = 0; kk < 16; kk++) {
    float4 a[4];
#pragma unroll
    for (int i = 0; i < 4; i++) {
      int r = r0 + i;
      float4 v = (r < n) ? A4[(size_t)r * 16 + kk] : make_float4(0.f, 0.f, 0.f, 0.f);
      if (reluIn) {
        v.x = fmaxf(v.x, 0.f); v.y = fmaxf(v.y, 0.f);
        v.z = fmaxf(v.z, 0.f); v.w = fmaxf(v.w, 0.f);
      }
      a[i] = v;
    }
#pragma unroll
    for (int q = 0; q < 4; q++) {
      int k = kk * 4 + q;
      float w[CPT];
      if constexpr (CPT % 4 == 0) {
#pragma unroll
        for (int j = 0; j < CPT / 4; j++)
          *(float4*)&w[4 * j] = *(const float4*)&Ws[k * F + c0 + 4 * j];  // ds_read_b128
      } else {
#pragma unroll
        for (int j = 0; j < CPT; j++) w[j] = Ws[k * F + c0 + j];
      }
#pragma unroll
      for (int i = 0; i < 4; i++) {
        float av = q == 0 ? a[i].x : q == 1 ? a[i].y : q == 2 ? a[i].z : a[i].w;
#pragma unroll
        for (int j = 0; j < CPT; j++) acc[i][j] = fmaf(av, w[j], acc[i][j]);
      }
    }
  }

  float bv[CPT];
#pragma unroll
  for (int j = 0; j < CPT; j++) bv[j] = bias ? bias[c0 + j] : 0.f;
#pragma unroll
  for (int i = 0; i < 4; i++) {
    int r = r0 + i;
    if (r < n) {
      float* crow = C + (size_t)r * F + c0;
#pragma unroll
      for (int j = 0; j < CPT; j++) {
        float v = acc[i][j] + bv[j];
        if (reluOut) v = fmaxf(v, 0.f);
        crow[j] = v;
      }
    }
  }
}

// Per-node gather-reduce: one 64-lane wave per node, lane = feature.
// out[d] = h[d]*dinv[d]^2 + bias + sum_e h[col[e]]*dinv[col[e]]*dinv[d].
// 8-wide predicated unroll: 8 gathers in flight, no serial remainder tail.
__global__ __launch_bounds__(256) void aggregate_kernel(const float* __restrict__ h,
                                                        const int* __restrict__ row_ptr,
                                                        const int* __restrict__ col,
                                                        const float* __restrict__ dinv,
                                                        const float* __restrict__ bias,
                                                        float* __restrict__ out) {
  int d = blockIdx.x * 4 + (threadIdx.x >> 6);
  int lane = threadIdx.x & 63;
  if (d >= N_NODES) return;
  int e0 = row_ptr[d], e1 = row_ptr[d + 1];
  float dv = dinv[d];
  float acc[8];
  acc[0] = fmaf(h[(size_t)d * 64 + lane], dv * dv, bias[lane]);
#pragma unroll
  for (int k = 1; k < 8; k++) acc[k] = 0.f;

  for (int e = e0; e < e1; e += 8) {
    int c[8];
#pragma unroll
    for (int k = 0; k < 8; k++) c[k] = (e + k < e1) ? col[e + k] : 0;
    float w[8];
#pragma unroll
    for (int k = 0; k < 8; k++) w[k] = (e + k < e1) ? dinv[c[k]] * dv : 0.f;
    float hv[8];
#pragma unroll
    for (int k = 0; k < 8; k++) hv[k] = h[(size_t)c[k] * 64 + lane];
#pragma unroll
    for (int k = 0; k < 8; k++) acc[k] = fmaf(hv[k], w[k], acc[k]);
  }
  float r = ((acc[0] + acc[1]) + (acc[2] + acc[3])) + ((acc[4] + acc[5]) + (acc[6] + acc[7]));
  out[(size_t)d * 64 + lane] = r;
}

}  // namespace

extern "C" void kernel_launch(void* const* d_in, const int* in_sizes, int n_in,
                              void* d_out, int out_size, void* d_ws, size_t ws_size,
                              hipStream_t stream) {
  const float* x   = (const float*)d_in[0];
  const void*  ei  = d_in[1];
  const float* W1  = (const float*)d_in[2];
  const float* b1  = (const float*)d_in[3];
  const float* W2  = (const float*)d_in[4];
  const float* b2  = (const float*)d_in[5];
  const float* Wm1 = (const float*)d_in[6];
  const float* bm1 = (const float*)d_in[7];
  const float* Wm2 = (const float*)d_in[8];
  const float* bm2 = (const float*)d_in[9];
  float* out = (float*)d_out;

  char* ws = (char*)d_ws;
  size_t off = 0;
  auto alloc = [&](size_t bytes) -> void* {
    void* p = ws + off;
    off = (off + bytes + 511) & ~(size_t)511;
    return p;
  };
  int*      flag      = (int*)     alloc(4);
  int*      bucketCnt = (int*)     alloc((size_t)NBUCK * 4);
  unsigned* tmp       = (unsigned*)alloc((size_t)NBUCK * CAP * 4);  // 6.4 MB
  int*      colA      = (int*)     alloc((size_t)N_EDGES * 4);
  int*      rowp      = (int*)     alloc((size_t)(N_NODES + 1) * 4);
  float*    dinv      = (float*)   alloc((size_t)N_NODES * 4);
  float*    hA        = (float*)   alloc((size_t)N_NODES * 64 * 4);
  float*    hB        = (float*)   alloc((size_t)N_NODES * 64 * 4);
  (void)ws_size; (void)in_sizes; (void)n_in; (void)out_size;

  dim3 b256(256);
  int gGemm = (N_NODES + 127) / 128;
  int gAgg  = (N_NODES + 3) / 4;
  int gBkt  = (N_EDGES + EPB_A - 1) / EPB_A;

  // graph preprocessing (shared by both convs): 2-pass bucket sort -> CSR
  zero_detect_kernel<<<1, b256, 0, stream>>>(bucketCnt, flag, (const unsigned int*)ei);
  bucket_kernel<<<gBkt, b256, 0, stream>>>(ei, flag, bucketCnt, tmp);
  csr_kernel<<<NBUCK, dim3(512), 0, stream>>>(tmp, bucketCnt, colA, rowp, dinv);

  // conv1: hA = x@W1; hB = aggregate(hA) + b1
  gemm_kernel<64><<<gGemm, b256, 0, stream>>>(x, W1, nullptr, hA, N_NODES, 0, 0);
  aggregate_kernel<<<gAgg, b256, 0, stream>>>(hA, rowp, colA, dinv, b1, hB);

  // conv2: hA = relu(hB)@W2; hB = aggregate(hA) + b2
  gemm_kernel<64><<<gGemm, b256, 0, stream>>>(hB, W2, nullptr, hA, N_NODES, 1, 0);
  aggregate_kernel<<<gAgg, b256, 0, stream>>>(hA, rowp, colA, dinv, b2, hB);

  // MLP: hA = relu(hB@Wm1+bm1); out = hA@Wm2+bm2
  gemm_kernel<64><<<gGemm, b256, 0, stream>>>(hB, Wm1, bm1, hA, N_NODES, 0, 1);
  gemm_kernel<40><<<gGemm, b256, 0, stream>>>(hA, Wm2, bm2, out, N_NODES, 0, 0);
}

// Round 5
// 299.977 us; speedup vs baseline: 2.3036x; 1.2750x over previous
//
#include <hip/hip_runtime.h>
#include <hip/hip_bf16.h>

// GCN: h1 = relu(GCNConv(x,W1,b1)); h2 = GCNConv(h1,W2,b2);
//      h3 = relu(h2@Wm1+bm1); out = h3@Wm2+bm2
// GCNConv(x,W,b): h = x@W; agg[d] = sum_{e:dst=d} h[src]*dinv[src]*dinv[d]
//                 + h[d]*dinv[d]^2 + b
// R2: CSR-by-dst gather-reduce replaced scatter atomics (10x write amp).
// R4: 2-pass XCD-local bucket sort (fill_kernel had 8x write amp).
// R5: aggregate was vmem-instr bound (R4: 3 loads/edge, 90us). Fold dinv[src]
//     into the GEMM epilogue: g = (x@W)*dinv, so agg = dinv[d]*(g[d]+SUM g[c])+b
//     -- edge weights vanish. CSR rows padded to multiples of 8 with sentinel
//     col -> zero row g[N_NODES]: col read as 2 broadcast int4 per 8 edges,
//     zero predication, pure gather+add loop (10 vmem instrs / 8 edges).

namespace {

constexpr int N_NODES = 100000;
constexpr int N_EDGES = 1000000;
constexpr int NBUCK = (N_NODES + 511) / 512;  // 196 buckets of 512 nodes
constexpr int CAP = 8192;      // bucket capacity (padded mean ~6963, sd ~88)
constexpr int EPB_A = 2048;    // edges per passA block

// Zero bucket counters + int32/int64 detection for edge_index.
// int64 high halves of values < 2^31 are all zero; int32 node ids are not.
__global__ __launch_bounds__(256) void zero_detect_kernel(int* bucketCnt, int* flag,
                                                          const unsigned int* __restrict__ w) {
  int t = threadIdx.x;
  if (t < NBUCK) bucketCnt[t] = 0;
  if (t == 0) *flag = 0;
  __syncthreads();
  unsigned any = 0;
  for (int s = 0; s < 8; s++) {
    long long pos = ((long long)(t * 8 + s) * 104729LL) % N_EDGES;
    any |= w[2 * pos + 1];
  }
  if (any) atomicOr(flag, 1);  // 1 => int32
}

// passA: partition edges into NBUCK buckets by dst>>9. Packed word =
// (src<<9)|(dst&511) (src<2^17 fits). Block-local LDS histogram, one global
// atomicAdd per touched bucket, per-block contiguous runs into tmp segments.
__global__ __launch_bounds__(256) void bucket_kernel(const void* __restrict__ ei,
                                                     const int* __restrict__ flag,
                                                     int* __restrict__ bucketCnt,
                                                     unsigned* __restrict__ tmp) {
  __shared__ int hist[NBUCK];
  __shared__ int basePB[NBUCK];
  __shared__ int cur[NBUCK];
  int t = threadIdx.x;
  if (t < NBUCK) { hist[t] = 0; cur[t] = 0; }
  __syncthreads();

  int e0 = blockIdx.x * EPB_A;
  int is32 = *flag;
  unsigned wreg[8];
  int breg[8];
#pragma unroll
  for (int k = 0; k < 8; k++) {
    int e = e0 + k * 256 + t;
    breg[k] = -1;
    if (e < N_EDGES) {
      int s, d;
      if (is32) {
        const int* p = (const int*)ei;
        s = p[e]; d = p[N_EDGES + e];
      } else {
        const long long* p = (const long long*)ei;
        s = (int)p[e]; d = (int)p[N_EDGES + e];
      }
      wreg[k] = ((unsigned)s << 9) | (unsigned)(d & 511);
      breg[k] = d >> 9;
      atomicAdd(&hist[breg[k]], 1);
    }
  }
  __syncthreads();
  if (t < NBUCK) basePB[t] = hist[t] ? atomicAdd(&bucketCnt[t], hist[t]) : 0;
  __syncthreads();
#pragma unroll
  for (int k = 0; k < 8; k++) {
    if (breg[k] >= 0) {
      int r = atomicAdd(&cur[breg[k]], 1);
      tmp[(size_t)breg[k] * CAP + basePB[breg[k]] + r] = wreg[k];
    }
  }
}

// passB: one block per bucket (fixed CAP-sized segment -> no cross-bucket
// scan). Stage bucket in LDS, 512-bin counting sort, rows padded to mult 8
// with sentinel N_NODES; emit row_start/row_end + dinv.
__global__ __launch_bounds__(512) void csr_kernel(const unsigned* __restrict__ tmp,
                                                  const int* __restrict__ bucketCnt,
                                                  int* __restrict__ col,
                                                  int* __restrict__ row_start,
                                                  int* __restrict__ row_end,
                                                  float* __restrict__ dinv) {
  __shared__ int sc[512];
  __shared__ int hist[512];
  __shared__ unsigned stage[CAP];
  int b = blockIdx.x, t = threadIdx.x;
  int myCnt = bucketCnt[b];
  int base = b * CAP;

  hist[t] = 0;
  __syncthreads();
  for (int i = t; i < myCnt; i += 512) {
    unsigned w = tmp[(size_t)base + i];
    stage[i] = w;
    atomicAdd(&hist[w & 511u], 1);
  }
  __syncthreads();

  int deg = hist[t];
  int pdeg = (deg + 7) & ~7;  // pad each row to multiple of 8 (16B-aligned)
  sc[t] = pdeg;
  __syncthreads();
#pragma unroll
  for (int off = 1; off < 512; off <<= 1) {
    int u = (t >= off) ? sc[t - off] : 0;
    __syncthreads();
    sc[t] += u;
    __syncthreads();
  }
  int pexcl = sc[t] - pdeg;
  int d = b * 512 + t;
  if (d < N_NODES) {
    row_start[d] = base + pexcl;
    row_end[d] = base + pexcl + pdeg;
    dinv[d] = rsqrtf((float)deg + 1.0f);
  }
  __syncthreads();
  hist[t] = pexcl;  // reuse as write cursor
  __syncthreads();
  for (int i = t; i < myCnt; i += 512) {
    unsigned w = stage[i];
    int pos = atomicAdd(&hist[w & 511u], 1);
    col[base + pos] = (int)(w >> 9);
  }
  for (int j = deg; j < pdeg; j++) col[base + pexcl + j] = N_NODES;  // sentinel -> zero row
}

// C[n,F] = op(A[n,64]) @ W[64,F] (+bias)(relu)(*rowScale). Block: 128 rows,
// 256 thr, thread = 4 rows x (F/8) cols. W staged in LDS; A read as float4.
// padZero: also zero row n of C (the sentinel row gathered by aggregate).
template <int F>
__global__ __launch_bounds__(256) void gemm_kernel(const float* __restrict__ A, const float* __restrict__ W,
                                                   const float* __restrict__ bias, float* __restrict__ C,
                                                   int n, int reluIn, int reluOut,
                                                   const float* __restrict__ rowScale, int padZero) {
  constexpr int CPT = F / 8;
  __shared__ float Ws[64 * F];
  int t = threadIdx.x;
  if (padZero && blockIdx.x == 0 && t < F / 4)
    ((float4*)&C[(size_t)n * F])[t] = make_float4(0.f, 0.f, 0.f, 0.f);
  for (int i = t; i < 64 * F / 4; i += 256) ((float4*)Ws)[i] = ((const float4*)W)[i];
  __syncthreads();

  int rg = t >> 3, cg = t & 7;
  int r0 = blockIdx.x * 128 + rg * 4;
  int c0 = cg * CPT;

  float acc[4][CPT];
#pragma unroll
  for (int i = 0; i < 4; i++)
#pragma unroll
    for (int j = 0; j < CPT; j++) acc[i][j] = 0.f;

  const float4* A4 = (const float4*)A;
  for (int kk = 0; kk < 16; kk++) {
    float4 a[4];
#pragma unroll
    for (int i = 0; i < 4; i++) {
      int r = r0 + i;
      float4 v = (r < n) ? A4[(size_t)r * 16 + kk] : make_float4(0.f, 0.f, 0.f, 0.f);
      if (reluIn) {
        v.x = fmaxf(v.x, 0.f); v.y = fmaxf(v.y, 0.f);
        v.z = fmaxf(v.z, 0.f); v.w = fmaxf(v.w, 0.f);
      }
      a[i] = v;
    }
#pragma unroll
    for (int q = 0; q < 4; q++) {
      int k = kk * 4 + q;
      float w[CPT];
      if constexpr (CPT % 4 == 0) {
#pragma unroll
        for (int j = 0; j < CPT / 4; j++)
          *(float4*)&w[4 * j] = *(const float4*)&Ws[k * F + c0 + 4 * j];  // ds_read_b128
      } else {
#pragma unroll
        for (int j = 0; j < CPT; j++) w[j] = Ws[k * F + c0 + j];
      }
#pragma unroll
      for (int i = 0; i < 4; i++) {
        float av = q == 0 ? a[i].x : q == 1 ? a[i].y : q == 2 ? a[i].z : a[i].w;
#pragma unroll
        for (int j = 0; j < CPT; j++) acc[i][j] = fmaf(av, w[j], acc[i][j]);
      }
    }
  }

  float bv[CPT];
#pragma unroll
  for (int j = 0; j < CPT; j++) bv[j] = bias ? bias[c0 + j] : 0.f;
#pragma unroll
  for (int i = 0; i < 4; i++) {
    int r = r0 + i;
    if (r < n) {
      float s = rowScale ? rowScale[r] : 1.0f;
      float* crow = C + (size_t)r * F + c0;
#pragma unroll
      for (int j = 0; j < CPT; j++) {
        float v = acc[i][j] + bv[j];
        if (reluOut) v = fmaxf(v, 0.f);
        crow[j] = v * s;
      }
    }
  }
}

// Per-node gather-reduce on pre-scaled g: one wave per node, lane = feature.
// out[d] = dinv[d]*(g[d] + SUM_e g[col[e]]) + bias. Rows padded to mult 8
// (pad cols hit the zero row), so the loop is 2 broadcast int4 col loads +
// 8 independent gathers + 8 adds per iteration, no predication.
__global__ __launch_bounds__(256) void aggregate_kernel(const float* __restrict__ g,
                                                        const int* __restrict__ col,
                                                        const int* __restrict__ row_start,
                                                        const int* __restrict__ row_end,
                                                        const float* __restrict__ dinv,
                                                        const float* __restrict__ bias,
                                                        float* __restrict__ out) {
  int d = blockIdx.x * 4 + (threadIdx.x >> 6);
  int lane = threadIdx.x & 63;
  if (d >= N_NODES) return;
  int e0 = row_start[d], e1 = row_end[d];
  float acc0 = g[(size_t)d * 64 + lane];  // self term (dinv folded in g)
  float acc1 = 0.f, acc2 = 0.f, acc3 = 0.f;
  float acc4 = 0.f, acc5 = 0.f, acc6 = 0.f, acc7 = 0.f;
  for (int e = e0; e < e1; e += 8) {
    int4 ca = *(const int4*)(col + e);      // broadcast, 16B aligned
    int4 cb = *(const int4*)(col + e + 4);
    float h0 = g[(size_t)ca.x * 64 + lane];
    float h1 = g[(size_t)ca.y * 64 + lane];
    float h2 = g[(size_t)ca.z * 64 + lane];
    float h3 = g[(size_t)ca.w * 64 + lane];
    float h4 = g[(size_t)cb.x * 64 + lane];
    float h5 = g[(size_t)cb.y * 64 + lane];
    float h6 = g[(size_t)cb.z * 64 + lane];
    float h7 = g[(size_t)cb.w * 64 + lane];
    acc0 += h0; acc1 += h1; acc2 += h2; acc3 += h3;
    acc4 += h4; acc5 += h5; acc6 += h6; acc7 += h7;
  }
  float r = ((acc0 + acc1) + (acc2 + acc3)) + ((acc4 + acc5) + (acc6 + acc7));
  out[(size_t)d * 64 + lane] = fmaf(r, dinv[d], bias[lane]);
}

}  // namespace

extern "C" void kernel_launch(void* const* d_in, const int* in_sizes, int n_in,
                              void* d_out, int out_size, void* d_ws, size_t ws_size,
                              hipStream_t stream) {
  const float* x   = (const float*)d_in[0];
  const void*  ei  = d_in[1];
  const float* W1  = (const float*)d_in[2];
  const float* b1  = (const float*)d_in[3];
  const float* W2  = (const float*)d_in[4];
  const float* b2  = (const float*)d_in[5];
  const float* Wm1 = (const float*)d_in[6];
  const float* bm1 = (const float*)d_in[7];
  const float* Wm2 = (const float*)d_in[8];
  const float* bm2 = (const float*)d_in[9];
  float* out = (float*)d_out;

  char* ws = (char*)d_ws;
  size_t off = 0;
  auto alloc = [&](size_t bytes) -> void* {
    void* p = ws + off;
    off = (off + bytes + 511) & ~(size_t)511;
    return p;
  };
  int*      flag      = (int*)     alloc(4);
  int*      bucketCnt = (int*)     alloc((size_t)NBUCK * 4);
  unsigned* tmp       = (unsigned*)alloc((size_t)NBUCK * CAP * 4);  // 6.4 MB
  int*      colA      = (int*)     alloc((size_t)NBUCK * CAP * 4);  // 6.4 MB
  int*      rowS      = (int*)     alloc((size_t)N_NODES * 4);
  int*      rowE      = (int*)     alloc((size_t)N_NODES * 4);
  float*    dinv      = (float*)   alloc((size_t)N_NODES * 4);
  float*    hA        = (float*)   alloc((size_t)(N_NODES + 1) * 64 * 4);  // +1 zero row
  float*    hB        = (float*)   alloc((size_t)N_NODES * 64 * 4);
  (void)ws_size; (void)in_sizes; (void)n_in; (void)out_size;

  dim3 b256(256);
  int gGemm = (N_NODES + 127) / 128;
  int gAgg  = (N_NODES + 3) / 4;
  int gBkt  = (N_EDGES + EPB_A - 1) / EPB_A;

  // graph preprocessing (shared by both convs): 2-pass bucket sort -> CSR
  zero_detect_kernel<<<1, b256, 0, stream>>>(bucketCnt, flag, (const unsigned int*)ei);
  bucket_kernel<<<gBkt, b256, 0, stream>>>(ei, flag, bucketCnt, tmp);
  csr_kernel<<<NBUCK, dim3(512), 0, stream>>>(tmp, bucketCnt, colA, rowS, rowE, dinv);

  // conv1: hA = (x@W1)*dinv (+zero pad row); hB = dinv*(self+SUM)+b1
  gemm_kernel<64><<<gGemm, b256, 0, stream>>>(x, W1, nullptr, hA, N_NODES, 0, 0, dinv, 1);
  aggregate_kernel<<<gAgg, b256, 0, stream>>>(hA, colA, rowS, rowE, dinv, b1, hB);

  // conv2: hA = (relu(hB)@W2)*dinv; hB = dinv*(self+SUM)+b2
  gemm_kernel<64><<<gGemm, b256, 0, stream>>>(hB, W2, nullptr, hA, N_NODES, 1, 0, dinv, 1);
  aggregate_kernel<<<gAgg, b256, 0, stream>>>(hA, colA, rowS, rowE, dinv, b2, hB);

  // MLP: hA = relu(hB@Wm1+bm1); out = hA@Wm2+bm2
  gemm_kernel<64><<<gGemm, b256, 0, stream>>>(hB, Wm1, bm1, hA, N_NODES, 0, 1, nullptr, 0);
  gemm_kernel<40><<<gGemm, b256, 0, stream>>>(hA, Wm2, bm2, out, N_NODES, 0, 0, nullptr, 0);
}